// Round 8
// baseline (1152.266 us; speedup 1.0000x reference)
//
#include <hip/hip_runtime.h>
#include <math.h>

// ============================================================================
// DoubleJpeg round 7: conflict-free LDS layout in convM ([px][q][8ic]
// interleave -> B-reads are contiguous 1KB/wave) + occupancy 3->4 blocks/CU.
// Everything else identical to round 6 (passed, absmax 9.8e-4).
// Arena A (62.91 MB): xd(fp32) -> pre1a A(raw) -> P1 -> P2 -> actT(fp16)
// Arena B (62.91 MB): feat(fp32) -> pre1b Bb -> C2 -> D3
// ============================================================================

typedef __attribute__((ext_vector_type(8))) _Float16 f16x8;
typedef __attribute__((ext_vector_type(4))) float f32x4;

#define GAMMA_F 1.0e6f

__device__ __forceinline__ unsigned short f2h(float f) {
  _Float16 h = (_Float16)f;
  union { _Float16 h; unsigned short u; } x; x.h = h; return x.u;
}
__device__ __forceinline__ float h2f(unsigned short u) {
  union { unsigned short u; _Float16 h; } x; x.u = u; return (float)x.h;
}

// ---------------------------------------------------------------- DCT kernel
__global__ __launch_bounds__(256) void k_dct(const float* __restrict__ x,
                                             const float* __restrict__ basis,
                                             float* __restrict__ xd) {
  __shared__ float bT[4096];
  __shared__ float pix[4][64];
  int tid = threadIdx.x;
  for (int e = tid; e < 4096; e += 256)
    bT[e] = basis[(e & 63) * 64 + (e >> 6)];
  __syncthreads();
  int w = tid >> 6, lane = tid & 63;
  int b = blockIdx.x >> 3;
  int br = ((blockIdx.x & 7) << 2) + w;
  const float* xb = x + (size_t)b * 65536;
  float* xdb = xd + (size_t)b * 65536;
  for (int bc = 0; bc < 32; ++bc) {
    __syncthreads();
    pix[w][lane] = xb[(br * 8 + (lane >> 3)) * 256 + bc * 8 + (lane & 7)];
    __syncthreads();
    float acc = 0.f;
#pragma unroll
    for (int p = 0; p < 64; ++p)
      acc = fmaf(bT[p * 64 + lane], pix[w][p], acc);
    xdb[lane * 1024 + br * 32 + bc] = acc;
  }
}

// ------------------------------- counting soft histogram (no atomics) -> feat
__global__ __launch_bounds__(256) void k_hist(const float* __restrict__ xd,
                                              float* __restrict__ feat) {
  __shared__ float px[1024];
  __shared__ float part[242];
  __shared__ float tot[121];
  int tid = threadIdx.x;
  int bc = blockIdx.x;
  int b = bc >> 6, c = bc & 63;
  const float* p = xd + (size_t)bc * 1024;
  for (int e = tid; e < 1024; e += 256) px[e] = p[e];
  __syncthreads();
  if (tid < 242) {
    int j = tid >> 1;
    float bj = (float)(j - 60);
    int i0 = (tid & 1) * 512;
    float cnt = 0.f;
    for (int i = i0; i < i0 + 512; ++i) {
      float d = px[i] - bj;
      float step = d > 0.f ? 1.f : 0.f;
      cnt += step;
      if (fabsf(d) < 2e-5f)
        cnt += 1.f / (1.f + expf(-GAMMA_F * d)) - step;
    }
    part[tid] = cnt;
  }
  __syncthreads();
  if (tid < 121) tot[tid] = part[2 * tid] + part[2 * tid + 1];
  __syncthreads();
  if (tid < 120)
    feat[((size_t)b * 120 + tid) * 64 + c] = (tot[tid] - tot[tid + 1]) * (1.f / 1024.f);
}

// ------------------------------------------- weight prep: fp32 -> fp16
__global__ __launch_bounds__(256) void k_prepw(const float* __restrict__ w,
                                               unsigned short* __restrict__ wt,
                                               int OC, int IC) {
  int n = OC * IC * 25;
  int idx = blockIdx.x * 256 + threadIdx.x;
  if (idx >= n) return;
  int t = idx / (OC * IC);
  int r = idx % (OC * IC);
  int o = r / IC, i = r % IC;
  wt[idx] = f2h(w[(o * IC + i) * 25 + t]);
}

// ----------------------------------------------- conv1a (CIN=1), direct fp32
__global__ __launch_bounds__(256) void k_conv1a(const float* __restrict__ in,
                                                const float* __restrict__ wgt,
                                                unsigned short* __restrict__ out) {
  __shared__ float tile[20 * 21];
  int tx = threadIdx.x & 15, ty = threadIdx.x >> 4;
  int tileX = (blockIdx.x & 3) * 16, tileY = (blockIdx.x >> 2) * 16;
  int b = blockIdx.y, ocb = blockIdx.z * 8;
  const float* inc = in + (size_t)b * 7680;
  for (int e = threadIdx.x; e < 400; e += 256) {
    int ly = e / 20, lx = e % 20;
    int gy = tileY - 2 + ly, gx = tileX - 2 + lx;
    float v = 0.f;
    if ((unsigned)gy < 120u && (unsigned)gx < 64u) v = inc[gy * 64 + gx];
    tile[ly * 21 + lx] = v;
  }
  __syncthreads();
  float tv[25];
#pragma unroll
  for (int dy = 0; dy < 5; ++dy)
#pragma unroll
    for (int dx = 0; dx < 5; ++dx)
      tv[dy * 5 + dx] = tile[(ty + dy) * 21 + tx + dx];
  float acc[8];
#pragma unroll
  for (int o = 0; o < 8; ++o) {
    const float* wo = wgt + (size_t)(ocb + o) * 25;
    float a = 0.f;
#pragma unroll
    for (int t = 0; t < 25; ++t) a = fmaf(tv[t], wo[t], a);
    acc[o] = a;
  }
  int oy = tileY + ty, ox = tileX + tx;
  if (oy < 120) {
    size_t base = (((size_t)b * 120 + oy) * 64 + ox) * 64 + ocb;
    ushort4 p0, p1;
    p0.x = f2h(acc[0]); p0.y = f2h(acc[1]); p0.z = f2h(acc[2]); p0.w = f2h(acc[3]);
    p1.x = f2h(acc[4]); p1.y = f2h(acc[5]); p1.z = f2h(acc[6]); p1.w = f2h(acc[7]);
    *(ushort4*)(out + base) = p0;
    *(ushort4*)(out + base + 4) = p1;
  }
}

// ---------------------------------------------- MFMA implicit-GEMM 5x5 conv
// NHWC fp16. Wave: 4 M-tiles (64 oc) x 4 N-tiles (16 px each).
// LDS layout [px][q][8ic] (64B per pixel): wave B-read = 16 consecutive px
// x 64B = contiguous 1KB -> conflict-free; staging writes thread-contiguous.
// PREBN: BN+ReLU applied to in-bounds pixels during staging; halo stays 0.
template <int CIN, int H, int W, int NT, int OC, bool PREBN>
__global__ __launch_bounds__(256, 4) void k_convM(const unsigned short* __restrict__ in,
                                                  const unsigned short* __restrict__ wt,
                                                  unsigned short* __restrict__ out,
                                                  const float* __restrict__ pst,
                                                  const float* __restrict__ pg,
                                                  const float* __restrict__ pbe) {
  constexpr int XC = W / 16, RPW = NT / XC, WGR = 4 * RPW;
  constexpr int LW = W + 4, LR = WGR + 4, NPX = LR * LW;
  __shared__ unsigned short lds[NPX * 4 * 8];
  int tid = threadIdx.x;
  int w = tid >> 6, lane = tid & 63, l15 = lane & 15, q = lane >> 4;
  int q4 = tid & 3;
  int y0 = blockIdx.x * WGR, b = blockIdx.y, oc0 = blockIdx.z * 64;
  f32x4 acc[4][NT];
#pragma unroll
  for (int mt = 0; mt < 4; ++mt)
#pragma unroll
    for (int nt = 0; nt < NT; ++nt) acc[mt][nt] = 0.f;

  for (int icb = 0; icb < CIN / 32; ++icb) {
    float s8[8], a8[8];
    if (PREBN) {
      int cb = icb * 32 + q4 * 8;
#pragma unroll
      for (int j = 0; j < 8; ++j) {
        float m = pst[cb + j], iv = pst[CIN + cb + j];
        s8[j] = pg[cb + j] * iv;
        a8[j] = pbe[cb + j] - m * s8[j];
      }
    }
    __syncthreads();
    for (int e = tid; e < NPX * 4; e += 256) {
      int px = e >> 2;                 // e&3 == q4 (invariant per thread)
      int lr = px / LW, c = px % LW;
      int y = y0 - 2 + lr, x = c - 2;
      f16x8 v = (f16x8)0;
      if ((unsigned)y < (unsigned)H && (unsigned)x < (unsigned)W) {
        v = *(const f16x8*)(in + (((size_t)b * H + y) * W + x) * CIN + icb * 32 + q4 * 8);
        if (PREBN) {
#pragma unroll
          for (int j = 0; j < 8; ++j) {
            float f = fmaf((float)v[j], s8[j], a8[j]);
            v[j] = (_Float16)(f > 0.f ? f : 0.f);
          }
        }
      }
      *(f16x8*)&lds[(size_t)e * 8] = v;  // e = px*4 + q4 -> [px][q][8ic]
    }
    __syncthreads();
    const unsigned short* wp0 = wt + (size_t)(oc0 + l15) * CIN + icb * 32 + q * 8;
    f16x8 avn[4];
#pragma unroll
    for (int mt = 0; mt < 4; ++mt)
      avn[mt] = *(const f16x8*)(wp0 + (size_t)(mt * 16) * CIN);
#pragma unroll
    for (int t = 0; t < 25; ++t) {
      int dy = t / 5, dx = t % 5;
      f16x8 avc[4];
#pragma unroll
      for (int mt = 0; mt < 4; ++mt) avc[mt] = avn[mt];
      if (t < 24) {
#pragma unroll
        for (int mt = 0; mt < 4; ++mt)
          avn[mt] = *(const f16x8*)(wp0 + (size_t)((t + 1) * OC + mt * 16) * CIN);
      }
#pragma unroll
      for (int nt = 0; nt < NT; ++nt) {
        int lr = w * RPW + nt / XC + dy;
        int c = (nt % XC) * 16 + l15 + dx;
        f16x8 bv = *(const f16x8*)&lds[(((size_t)lr * LW + c) * 4 + q) * 8];
#pragma unroll
        for (int mt = 0; mt < 4; ++mt)
          acc[mt][nt] = __builtin_amdgcn_mfma_f32_16x16x32_f16(avc[mt], bv, acc[mt][nt], 0, 0, 0);
      }
    }
  }
#pragma unroll
  for (int nt = 0; nt < NT; ++nt) {
    int y = y0 + w * RPW + nt / XC;
    if (y >= H) continue;
    int x = (nt % XC) * 16 + l15;
    size_t pbase = (((size_t)b * H + y) * W + x) * OC + oc0 + q * 4;
#pragma unroll
    for (int mt = 0; mt < 4; ++mt) {
      ushort4 pk;
      pk.x = f2h(acc[mt][nt][0]);
      pk.y = f2h(acc[mt][nt][1]);
      pk.z = f2h(acc[mt][nt][2]);
      pk.w = f2h(acc[mt][nt][3]);
      *(ushort4*)(out + pbase + mt * 16) = pk;
    }
  }
}

// ------------------- BN stats, vectorized f16x8 (fully coalesced 1KB/wave)
template <int C>
__global__ __launch_bounds__(256) void k_bnstatsv(const unsigned short* __restrict__ x,
                                                  float* __restrict__ acc,
                                                  int nIter) {
  constexpr int CV = C / 8, KPB = 256 / CV;
  __shared__ float r1[256][8], r2[256][8];
  int tid = threadIdx.x;
  int cv = tid % CV, kq = tid / CV;
  size_t row0 = (size_t)blockIdx.x * (KPB * nIter) + kq;
  const unsigned short* p = x + row0 * C + cv * 8;
  float s1[8], s2[8];
#pragma unroll
  for (int j = 0; j < 8; ++j) { s1[j] = 0.f; s2[j] = 0.f; }
  for (int it = 0; it < nIter; ++it) {
    f16x8 v = *(const f16x8*)(p + (size_t)it * KPB * C);
#pragma unroll
    for (int j = 0; j < 8; ++j) {
      float f = (float)v[j];
      s1[j] += f;
      s2[j] += f * f;
    }
  }
#pragma unroll
  for (int j = 0; j < 8; ++j) { r1[tid][j] = s1[j]; r2[tid][j] = s2[j]; }
  __syncthreads();
  if (tid < C) {
    int cv0 = tid >> 3, e = tid & 7;
    float t1 = 0.f, t2 = 0.f;
    for (int k = 0; k < KPB; ++k) {
      t1 += r1[k * CV + cv0][e];
      t2 += r2[k * CV + cv0][e];
    }
    atomicAdd(&acc[tid], t1);
    atomicAdd(&acc[C + tid], t2);
  }
}

__global__ __launch_bounds__(256) void k_bnfin(const float* __restrict__ acc,
                                               float* __restrict__ stats,
                                               int C, float invN) {
  int c = threadIdx.x + blockIdx.x * 256;
  if (c >= C) return;
  float m = acc[c] * invN;
  float v = acc[C + c] * invN - m * m;
  stats[c] = m;
  stats[C + c] = rsqrtf(v + 1e-5f);
}

// --------------------------------------- BN+ReLU+maxpool2 NHWC (x8 vec)
template <int C, int H, int W>
__global__ __launch_bounds__(256) void k_brp(const unsigned short* __restrict__ x,
                                             unsigned short* __restrict__ y,
                                             const float* __restrict__ stats,
                                             const float* __restrict__ g,
                                             const float* __restrict__ be) {
  constexpr int OH = H / 2, OW = W / 2, CV = C / 8;
  int idx = blockIdx.x * 256 + threadIdx.x;   // [b][oy][ox][cv]
  int cv = idx % CV;
  int t = idx / CV;
  int ox = t % OW; t /= OW;
  int oy = t % OH;
  int b = t / OH;
  int c0 = cv * 8;
  const unsigned short* p = x + ((size_t)(b * H + oy * 2) * W + ox * 2) * C + c0;
  f16x8 v00 = *(const f16x8*)p;
  f16x8 v01 = *(const f16x8*)(p + C);
  f16x8 v10 = *(const f16x8*)(p + (size_t)W * C);
  f16x8 v11 = *(const f16x8*)(p + (size_t)W * C + C);
  f16x8 r;
#pragma unroll
  for (int j = 0; j < 8; ++j) {
    int c = c0 + j;
    float m = stats[c], iv = stats[C + c], gg = g[c], bb = be[c];
    float f0 = gg * (((float)v00[j] - m) * iv) + bb;
    float f1 = gg * (((float)v01[j] - m) * iv) + bb;
    float f2 = gg * (((float)v10[j] - m) * iv) + bb;
    float f3 = gg * (((float)v11[j] - m) * iv) + bb;
    f0 = f0 > 0.f ? f0 : 0.f;
    f1 = f1 > 0.f ? f1 : 0.f;
    f2 = f2 > 0.f ? f2 : 0.f;
    f3 = f3 > 0.f ? f3 : 0.f;
    float r01 = f0 > f1 ? f0 : f1;
    float r23 = f2 > f3 ? f2 : f3;
    r[j] = (_Float16)(r01 > r23 ? r01 : r23);
  }
  *(f16x8*)(y + (size_t)idx * 8) = r;
}

// ---- stage-3 BN+ReLU+pool + write into batch-major fc1 activations (fp16)
__global__ __launch_bounds__(256) void k_brp3t(const unsigned short* __restrict__ x,
                                               unsigned short* __restrict__ actT,
                                               const float* __restrict__ stats,
                                               const float* __restrict__ g,
                                               const float* __restrict__ be) {
  __shared__ float tile[64 * 65];
  int s = blockIdx.x;
  int oy = s >> 3, ox = s & 7;
  int ci = threadIdx.x & 63, bq = threadIdx.x >> 6;
  for (int cs = 0; cs < 4; ++cs) {
    int c = cs * 64 + ci;
    float m = stats[c], iv = stats[256 + c], gg = g[c], bb = be[c];
    __syncthreads();
    for (int b = bq; b < 64; b += 4) {
      float mx = 0.f;
#pragma unroll
      for (int qq = 0; qq < 4; ++qq) {
        int yy = oy * 2 + (qq >> 1), xx = ox * 2 + (qq & 1);
        float v = h2f(x[((size_t)(b * 30 + yy) * 16 + xx) * 256 + c]);
        v = gg * ((v - m) * iv) + bb;
        v = v > 0.f ? v : 0.f;
        mx = v > mx ? v : mx;
      }
      tile[ci * 65 + b] = mx;
    }
    __syncthreads();
    for (int e = threadIdx.x; e < 4096; e += 256) {
      int cc = e >> 6, bb2 = e & 63;
      actT[(size_t)bb2 * 30784 + 64 + (cs * 64 + cc) * 120 + s] = f2h(tile[cc * 65 + bb2]);
    }
  }
}

// -------------------- q rows of fc inputs + zero fc1 accumulator + BN accums
__global__ __launch_bounds__(256) void k_qinit(const float* __restrict__ q,
                                               unsigned short* __restrict__ actT,
                                               float* __restrict__ in2T,
                                               float* __restrict__ in3T,
                                               float* __restrict__ z1pre,
                                               float* __restrict__ bnacc) {
  int idx = blockIdx.x * 256 + threadIdx.x;
  if (idx < 32000) z1pre[idx] = 0.f;
  else if (idx < 33024) bnacc[idx - 32000] = 0.f;
  if (idx >= 4096) return;
  int b = idx >> 6, i = idx & 63;
  float v = q[idx];
  actT[(size_t)b * 30784 + i] = f2h(v);
  in2T[i * 64 + b] = v;
  in3T[i * 64 + b] = v;
}

// --------------------------------------------------------- fc1 (MFMA GEMM)
__global__ __launch_bounds__(256) void k_fc1m(const unsigned short* __restrict__ actT,
                                              const float* __restrict__ wgt,
                                              float* __restrict__ z1pre) {
  constexpr int IN = 30784;
  constexpr int KSTEPS = IN / 32;   // 962
  __shared__ float part[4][16][64];
  int tid = threadIdx.x;
  int w = tid >> 6, lane = tid & 63, l15 = lane & 15, q = lane >> 4;
  int ob = blockIdx.x * 16;
  int row = ob + l15; if (row > 499) row = 499;
  int kw = blockIdx.y * 4 + w;      // 0..31
  f32x4 acc[4];
#pragma unroll
  for (int nt = 0; nt < 4; ++nt) acc[nt] = 0.f;
  for (int s = kw; s < KSTEPS; s += 32) {
    int k0 = s * 32;
    const float4* wp = (const float4*)(wgt + (size_t)row * IN + k0 + q * 8);
    float4 wa = wp[0], wb = wp[1];
    f16x8 a;
    a[0] = (_Float16)wa.x; a[1] = (_Float16)wa.y;
    a[2] = (_Float16)wa.z; a[3] = (_Float16)wa.w;
    a[4] = (_Float16)wb.x; a[5] = (_Float16)wb.y;
    a[6] = (_Float16)wb.z; a[7] = (_Float16)wb.w;
#pragma unroll
    for (int nt = 0; nt < 4; ++nt) {
      f16x8 bv = *(const f16x8*)(actT + (size_t)(nt * 16 + l15) * IN + k0 + q * 8);
      acc[nt] = __builtin_amdgcn_mfma_f32_16x16x32_f16(a, bv, acc[nt], 0, 0, 0);
    }
  }
#pragma unroll
  for (int nt = 0; nt < 4; ++nt)
#pragma unroll
    for (int reg = 0; reg < 4; ++reg)
      part[w][q * 4 + reg][nt * 16 + l15] = acc[nt][reg];
  __syncthreads();
  for (int e = tid; e < 1024; e += 256) {
    int m = e >> 6, n = e & 63;
    float sum = part[0][m][n] + part[1][m][n] + part[2][m][n] + part[3][m][n];
    int o = ob + m;
    if (o < 500) atomicAdd(&z1pre[o * 64 + n], sum);
  }
}

__global__ __launch_bounds__(256) void k_fc1ep(const float* __restrict__ z1pre,
                                               const float* __restrict__ bias,
                                               float* __restrict__ in2T) {
  int idx = blockIdx.x * 256 + threadIdx.x;
  if (idx >= 500 * 64) return;
  int o = idx >> 6;
  float v = z1pre[idx] + bias[o];
  in2T[idx + 64 * 64] = v > 0.f ? v : 0.f;
}

__global__ __launch_bounds__(256) void k_fc_small(const float* __restrict__ inT,
                                                  const float* __restrict__ wgt,
                                                  const float* __restrict__ bias,
                                                  float* __restrict__ out,
                                                  int IN, int mode) {
  __shared__ float part[4][64];
  int o = blockIdx.x;
  int lane = threadIdx.x & 63, w = threadIdx.x >> 6;
  float acc = 0.f;
  for (int i = w; i < IN; i += 4)
    acc = fmaf(inT[(size_t)i * 64 + lane], wgt[(size_t)o * IN + i], acc);
  part[w][lane] = acc;
  __syncthreads();
  if (threadIdx.x < 64) {
    float s = part[0][lane] + part[1][lane] + part[2][lane] + part[3][lane] + bias[o];
    if (mode == 0) {
      s = s > 0.f ? s : 0.f;
      out[(64 + o) * 64 + lane] = s;
    } else {
      out[lane * 2 + o] = s;
    }
  }
}

// ============================================================================
extern "C" void kernel_launch(void* const* d_in, const int* in_sizes, int n_in,
                              void* d_out, int out_size, void* d_ws, size_t ws_size,
                              hipStream_t stream) {
  const float* x      = (const float*)d_in[0];
  const float* qvec   = (const float*)d_in[1];
  const float* basis  = (const float*)d_in[2];
  const float* w1a    = (const float*)d_in[3];
  const float* g1a    = (const float*)d_in[5];
  const float* be1a   = (const float*)d_in[6];
  const float* w1b    = (const float*)d_in[7];
  const float* g1b    = (const float*)d_in[9];
  const float* be1b   = (const float*)d_in[10];
  const float* w2a    = (const float*)d_in[11];
  const float* g2a    = (const float*)d_in[13];
  const float* be2a   = (const float*)d_in[14];
  const float* w3a    = (const float*)d_in[15];
  const float* g3a    = (const float*)d_in[17];
  const float* be3a   = (const float*)d_in[18];
  const float* fc1w   = (const float*)d_in[19];
  const float* fc1b   = (const float*)d_in[20];
  const float* fc2w   = (const float*)d_in[21];
  const float* fc2b   = (const float*)d_in[22];
  const float* fc3w   = (const float*)d_in[23];
  const float* fc3b   = (const float*)d_in[24];
  float* out = (float*)d_out;

  char* base = (char*)d_ws;
  constexpr size_t ARENA = 62914560;
  char* arenaA = base;
  char* arenaB = base + ARENA;
  char* sm     = base + 2 * ARENA;

  float*          xd   = (float*)arenaA;
  unsigned short* A    = (unsigned short*)arenaA;  // pre1a NHWC [64][120][64][64] (raw)
  unsigned short* P1   = (unsigned short*)arenaA;  // [64][60][32][64]
  unsigned short* P2   = (unsigned short*)arenaA;  // [64][30][16][128]
  unsigned short* actT = (unsigned short*)arenaA;  // [64][30784] fp16

  float*          feat = (float*)arenaB;           // [64][120][64] fp32
  unsigned short* Bb   = (unsigned short*)arenaB;  // pre1b [64][120][64][64]
  unsigned short* C2   = (unsigned short*)arenaB;  // [64][60][32][128]
  unsigned short* D3   = (unsigned short*)arenaB;  // [64][30][16][256]

  float* in2T = (float*)sm;                    // 144,384 B
  float* in3T = (float*)(sm + 144384);         // 144,384 B
  float* z1p  = (float*)(sm + 288768);         // 128,000 B
  float* ACC  = (float*)(sm + 416768);         // 4,096 B
  float* S1A  = (float*)(sm + 420864);
  float* S1B  = (float*)(sm + 421376);
  float* S2A  = (float*)(sm + 421888);
  float* S3A  = (float*)(sm + 422912);
  unsigned short* WT1 = (unsigned short*)(sm + 424960);   // 204,800 B
  unsigned short* WT2 = (unsigned short*)(sm + 834560);   // 409,600 B
  unsigned short* WT3 = (unsigned short*)(sm + 1653760);  // 1,638,400 B

  k_qinit<<<130, 256, 0, stream>>>(qvec, actT, in2T, in3T, z1p, ACC);
  k_prepw<<<400, 256, 0, stream>>>(w1b, WT1, 64, 64);
  k_prepw<<<800, 256, 0, stream>>>(w2a, WT2, 128, 64);
  k_prepw<<<3200, 256, 0, stream>>>(w3a, WT3, 256, 128);

  k_dct<<<64 * 8, 256, 0, stream>>>(x, basis, xd);
  k_hist<<<4096, 256, 0, stream>>>(xd, feat);

  // conv1a (direct) -> A (raw pre-activations), stats over A
  k_conv1a<<<dim3(32, 64, 8), 256, 0, stream>>>(feat, w1a, A);
  k_bnstatsv<64><<<240, 256, 0, stream>>>(A, ACC, 64);
  k_bnfin<<<1, 64, 0, stream>>>(ACC, S1A, 64, 1.f / 491520.f);

  // conv1b (MFMA, PREBN applies BN1a+ReLU during staging) -> Bb
  k_convM<64, 120, 64, 4, 64, true><<<dim3(30, 64, 1), 256, 0, stream>>>(
      A, WT1, Bb, S1A, g1a, be1a);
  k_bnstatsv<64><<<240, 256, 0, stream>>>(Bb, ACC + 128, 64);
  k_bnfin<<<1, 64, 0, stream>>>(ACC + 128, S1B, 64, 1.f / 491520.f);
  k_brp<64, 120, 64><<<3840, 256, 0, stream>>>(Bb, P1, S1B, g1b, be1b);

  // conv2a -> C2, stats, pool -> P2
  k_convM<64, 60, 32, 4, 128, false><<<dim3(8, 64, 2), 256, 0, stream>>>(
      P1, WT2, C2, S1A, g1a, be1a);
  k_bnstatsv<128><<<240, 256, 0, stream>>>(C2, ACC + 256, 32);
  k_bnfin<<<1, 128, 0, stream>>>(ACC + 256, S2A, 128, 1.f / 122880.f);
  k_brp<128, 60, 32><<<1920, 256, 0, stream>>>(C2, P2, S2A, g2a, be2a);

  // conv3a -> D3, stats, pool+transpose -> actT
  k_convM<128, 30, 16, 4, 256, false><<<dim3(2, 64, 4), 256, 0, stream>>>(
      P2, WT3, D3, S1A, g1a, be1a);
  k_bnstatsv<256><<<240, 256, 0, stream>>>(D3, ACC + 512, 16);
  k_bnfin<<<1, 256, 0, stream>>>(ACC + 512, S3A, 256, 1.f / 30720.f);
  k_qinit<<<130, 256, 0, stream>>>(qvec, actT, in2T, in3T, z1p, ACC);
  k_brp3t<<<120, 256, 0, stream>>>(D3, actT, S3A, g3a, be3a);

  // FC head
  k_fc1m<<<dim3(32, 8), 256, 0, stream>>>(actT, fc1w, z1p);
  k_fc1ep<<<125, 256, 0, stream>>>(z1p, fc1b, in2T);
  k_fc_small<<<500, 256, 0, stream>>>(in2T, fc2w, fc2b, in3T, 564, 0);
  k_fc_small<<<2, 256, 0, stream>>>(in3T, fc3w, fc3b, out, 564, 1);
}

// Round 9
// 944.994 us; speedup vs baseline: 1.2193x; 1.2193x over previous
//
#include <hip/hip_runtime.h>
#include <math.h>

// ============================================================================
// DoubleJpeg round 8: convM with (1) fragment-major weights -> each wave
// A-frag load is 1KB contiguous (was 16-segment gather), (2) 80B-per-pixel
// LDS slots (slot=px*5+q4) -> B-reads AND staging writes conflict-free.
// Arena A (62.91 MB): xd(fp32) -> pre1a A(raw) -> P1 -> P2 -> actT(fp16)
// Arena B (62.91 MB): feat(fp32) -> pre1b Bb -> C2 -> D3
// ============================================================================

typedef __attribute__((ext_vector_type(8))) _Float16 f16x8;
typedef __attribute__((ext_vector_type(4))) float f32x4;

#define GAMMA_F 1.0e6f

__device__ __forceinline__ unsigned short f2h(float f) {
  _Float16 h = (_Float16)f;
  union { _Float16 h; unsigned short u; } x; x.h = h; return x.u;
}
__device__ __forceinline__ float h2f(unsigned short u) {
  union { unsigned short u; _Float16 h; } x; x.u = u; return (float)x.h;
}

// ---------------------------------------------------------------- DCT kernel
__global__ __launch_bounds__(256) void k_dct(const float* __restrict__ x,
                                             const float* __restrict__ basis,
                                             float* __restrict__ xd) {
  __shared__ float bT[4096];
  __shared__ float pix[4][64];
  int tid = threadIdx.x;
  for (int e = tid; e < 4096; e += 256)
    bT[e] = basis[(e & 63) * 64 + (e >> 6)];
  __syncthreads();
  int w = tid >> 6, lane = tid & 63;
  int b = blockIdx.x >> 3;
  int br = ((blockIdx.x & 7) << 2) + w;
  const float* xb = x + (size_t)b * 65536;
  float* xdb = xd + (size_t)b * 65536;
  for (int bc = 0; bc < 32; ++bc) {
    __syncthreads();
    pix[w][lane] = xb[(br * 8 + (lane >> 3)) * 256 + bc * 8 + (lane & 7)];
    __syncthreads();
    float acc = 0.f;
#pragma unroll
    for (int p = 0; p < 64; ++p)
      acc = fmaf(bT[p * 64 + lane], pix[w][p], acc);
    xdb[lane * 1024 + br * 32 + bc] = acc;
  }
}

// ------------------------------- counting soft histogram (no atomics) -> feat
__global__ __launch_bounds__(256) void k_hist(const float* __restrict__ xd,
                                              float* __restrict__ feat) {
  __shared__ float px[1024];
  __shared__ float part[242];
  __shared__ float tot[121];
  int tid = threadIdx.x;
  int bc = blockIdx.x;
  int b = bc >> 6, c = bc & 63;
  const float* p = xd + (size_t)bc * 1024;
  for (int e = tid; e < 1024; e += 256) px[e] = p[e];
  __syncthreads();
  if (tid < 242) {
    int j = tid >> 1;
    float bj = (float)(j - 60);
    int i0 = (tid & 1) * 512;
    float cnt = 0.f;
    for (int i = i0; i < i0 + 512; ++i) {
      float d = px[i] - bj;
      float step = d > 0.f ? 1.f : 0.f;
      cnt += step;
      if (fabsf(d) < 2e-5f)
        cnt += 1.f / (1.f + expf(-GAMMA_F * d)) - step;
    }
    part[tid] = cnt;
  }
  __syncthreads();
  if (tid < 121) tot[tid] = part[2 * tid] + part[2 * tid + 1];
  __syncthreads();
  if (tid < 120)
    feat[((size_t)b * 120 + tid) * 64 + c] = (tot[tid] - tot[tid + 1]) * (1.f / 1024.f);
}

// --------------- weight prep: fp32 -> fp16, fragment-major layout
// out: wt[((t*(OC/16)+mt)*(IC/32)+icb)*512 + l15*32 + q*8 + j]
//    = w[oc=mt*16+l15][ic=icb*32+q*8+j][t]
__global__ __launch_bounds__(256) void k_prepw(const float* __restrict__ w,
                                               unsigned short* __restrict__ wt,
                                               int OC, int IC) {
  int n = OC * IC * 25;
  int idx = blockIdx.x * 256 + threadIdx.x;
  if (idx >= n) return;
  int j = idx & 7;
  int q = (idx >> 3) & 3;
  int l15 = (idx >> 5) & 15;
  int r = idx >> 9;
  int icb = r % (IC / 32);
  int r2 = r / (IC / 32);
  int mt = r2 % (OC / 16);
  int t = r2 / (OC / 16);
  int oc = mt * 16 + l15;
  int ic = icb * 32 + q * 8 + j;
  wt[idx] = f2h(w[((size_t)oc * IC + ic) * 25 + t]);
}

// ----------------------------------------------- conv1a (CIN=1), direct fp32
__global__ __launch_bounds__(256) void k_conv1a(const float* __restrict__ in,
                                                const float* __restrict__ wgt,
                                                unsigned short* __restrict__ out) {
  __shared__ float tile[20 * 21];
  int tx = threadIdx.x & 15, ty = threadIdx.x >> 4;
  int tileX = (blockIdx.x & 3) * 16, tileY = (blockIdx.x >> 2) * 16;
  int b = blockIdx.y, ocb = blockIdx.z * 8;
  const float* inc = in + (size_t)b * 7680;
  for (int e = threadIdx.x; e < 400; e += 256) {
    int ly = e / 20, lx = e % 20;
    int gy = tileY - 2 + ly, gx = tileX - 2 + lx;
    float v = 0.f;
    if ((unsigned)gy < 120u && (unsigned)gx < 64u) v = inc[gy * 64 + gx];
    tile[ly * 21 + lx] = v;
  }
  __syncthreads();
  float tv[25];
#pragma unroll
  for (int dy = 0; dy < 5; ++dy)
#pragma unroll
    for (int dx = 0; dx < 5; ++dx)
      tv[dy * 5 + dx] = tile[(ty + dy) * 21 + tx + dx];
  float acc[8];
#pragma unroll
  for (int o = 0; o < 8; ++o) {
    const float* wo = wgt + (size_t)(ocb + o) * 25;
    float a = 0.f;
#pragma unroll
    for (int t = 0; t < 25; ++t) a = fmaf(tv[t], wo[t], a);
    acc[o] = a;
  }
  int oy = tileY + ty, ox = tileX + tx;
  if (oy < 120) {
    size_t base = (((size_t)b * 120 + oy) * 64 + ox) * 64 + ocb;
    ushort4 p0, p1;
    p0.x = f2h(acc[0]); p0.y = f2h(acc[1]); p0.z = f2h(acc[2]); p0.w = f2h(acc[3]);
    p1.x = f2h(acc[4]); p1.y = f2h(acc[5]); p1.z = f2h(acc[6]); p1.w = f2h(acc[7]);
    *(ushort4*)(out + base) = p0;
    *(ushort4*)(out + base + 4) = p1;
  }
}

// ---------------------------------------------- MFMA implicit-GEMM 5x5 conv
// NHWC fp16. Wave: 4 M-tiles (64 oc) x 4 N-tiles (16 px each).
// LDS: 80B slot per pixel (slot=px*5+q4): B-reads (5px+q)%8 injective ->
// conflict-free; staging writes ~conflict-free. Weights fragment-major ->
// each A-frag load is 1KB contiguous.
template <int CIN, int H, int W, int NT, int OC, bool PREBN>
__global__ __launch_bounds__(256, 4) void k_convM(const unsigned short* __restrict__ in,
                                                  const unsigned short* __restrict__ wt,
                                                  unsigned short* __restrict__ out,
                                                  const float* __restrict__ pst,
                                                  const float* __restrict__ pg,
                                                  const float* __restrict__ pbe) {
  constexpr int XC = W / 16, RPW = NT / XC, WGR = 4 * RPW;
  constexpr int LW = W + 4, LR = WGR + 4, NPX = LR * LW;
  constexpr int MTS = (CIN / 32) * 512;       // per-mt frag stride (halfwords)
  constexpr int TS = (OC / 16) * MTS;         // per-tap frag stride
  __shared__ unsigned short lds[NPX * 40];    // 80B per pixel
  int tid = threadIdx.x;
  int w = tid >> 6, lane = tid & 63, l15 = lane & 15, q = lane >> 4;
  int q4 = tid & 3;
  int y0 = blockIdx.x * WGR, b = blockIdx.y, oc0 = blockIdx.z * 64;
  int z4 = blockIdx.z * 4;
  int lofs = (l15 * 4 + q) * 8;
  f32x4 acc[4][NT];
#pragma unroll
  for (int mt = 0; mt < 4; ++mt)
#pragma unroll
    for (int nt = 0; nt < NT; ++nt) acc[mt][nt] = 0.f;

  for (int icb = 0; icb < CIN / 32; ++icb) {
    float s8[8], a8[8];
    if (PREBN) {
      int cb = icb * 32 + q4 * 8;
#pragma unroll
      for (int j = 0; j < 8; ++j) {
        float m = pst[cb + j], iv = pst[CIN + cb + j];
        s8[j] = pg[cb + j] * iv;
        a8[j] = pbe[cb + j] - m * s8[j];
      }
    }
    __syncthreads();
    for (int e = tid; e < NPX * 4; e += 256) {
      int px = e >> 2;                 // e&3 == q4 (invariant per thread)
      int lr = px / LW, c = px % LW;
      int y = y0 - 2 + lr, x = c - 2;
      f16x8 v = (f16x8)0;
      if ((unsigned)y < (unsigned)H && (unsigned)x < (unsigned)W) {
        v = *(const f16x8*)(in + (((size_t)b * H + y) * W + x) * CIN + icb * 32 + q4 * 8);
        if (PREBN) {
#pragma unroll
          for (int j = 0; j < 8; ++j) {
            float f = fmaf((float)v[j], s8[j], a8[j]);
            v[j] = (_Float16)(f > 0.f ? f : 0.f);
          }
        }
      }
      *(f16x8*)&lds[(size_t)(px * 5 + q4) * 8] = v;
    }
    __syncthreads();
    const unsigned short* wbase = wt + (size_t)icb * 512 + lofs;
    f16x8 avn[4];
#pragma unroll
    for (int mt = 0; mt < 4; ++mt)
      avn[mt] = *(const f16x8*)(wbase + (size_t)(z4 + mt) * MTS);
#pragma unroll
    for (int t = 0; t < 25; ++t) {
      int dy = t / 5, dx = t % 5;
      f16x8 avc[4];
#pragma unroll
      for (int mt = 0; mt < 4; ++mt) avc[mt] = avn[mt];
      if (t < 24) {
#pragma unroll
        for (int mt = 0; mt < 4; ++mt)
          avn[mt] = *(const f16x8*)(wbase + (size_t)(t + 1) * TS + (size_t)(z4 + mt) * MTS);
      }
#pragma unroll
      for (int nt = 0; nt < NT; ++nt) {
        int lr = w * RPW + nt / XC + dy;
        int c = (nt % XC) * 16 + l15 + dx;
        f16x8 bv = *(const f16x8*)&lds[(size_t)((lr * LW + c) * 5 + q) * 8];
#pragma unroll
        for (int mt = 0; mt < 4; ++mt)
          acc[mt][nt] = __builtin_amdgcn_mfma_f32_16x16x32_f16(avc[mt], bv, acc[mt][nt], 0, 0, 0);
      }
    }
  }
#pragma unroll
  for (int nt = 0; nt < NT; ++nt) {
    int y = y0 + w * RPW + nt / XC;
    if (y >= H) continue;
    int x = (nt % XC) * 16 + l15;
    size_t pbase = (((size_t)b * H + y) * W + x) * OC + oc0 + q * 4;
#pragma unroll
    for (int mt = 0; mt < 4; ++mt) {
      ushort4 pk;
      pk.x = f2h(acc[mt][nt][0]);
      pk.y = f2h(acc[mt][nt][1]);
      pk.z = f2h(acc[mt][nt][2]);
      pk.w = f2h(acc[mt][nt][3]);
      *(ushort4*)(out + pbase + mt * 16) = pk;
    }
  }
}

// ------------------- BN stats, vectorized f16x8 (fully coalesced 1KB/wave)
template <int C>
__global__ __launch_bounds__(256) void k_bnstatsv(const unsigned short* __restrict__ x,
                                                  float* __restrict__ acc,
                                                  int nIter) {
  constexpr int CV = C / 8, KPB = 256 / CV;
  __shared__ float r1[256][8], r2[256][8];
  int tid = threadIdx.x;
  int cv = tid % CV, kq = tid / CV;
  size_t row0 = (size_t)blockIdx.x * (KPB * nIter) + kq;
  const unsigned short* p = x + row0 * C + cv * 8;
  float s1[8], s2[8];
#pragma unroll
  for (int j = 0; j < 8; ++j) { s1[j] = 0.f; s2[j] = 0.f; }
  for (int it = 0; it < nIter; ++it) {
    f16x8 v = *(const f16x8*)(p + (size_t)it * KPB * C);
#pragma unroll
    for (int j = 0; j < 8; ++j) {
      float f = (float)v[j];
      s1[j] += f;
      s2[j] += f * f;
    }
  }
#pragma unroll
  for (int j = 0; j < 8; ++j) { r1[tid][j] = s1[j]; r2[tid][j] = s2[j]; }
  __syncthreads();
  if (tid < C) {
    int cv0 = tid >> 3, e = tid & 7;
    float t1 = 0.f, t2 = 0.f;
    for (int k = 0; k < KPB; ++k) {
      t1 += r1[k * CV + cv0][e];
      t2 += r2[k * CV + cv0][e];
    }
    atomicAdd(&acc[tid], t1);
    atomicAdd(&acc[C + tid], t2);
  }
}

__global__ __launch_bounds__(256) void k_bnfin(const float* __restrict__ acc,
                                               float* __restrict__ stats,
                                               int C, float invN) {
  int c = threadIdx.x + blockIdx.x * 256;
  if (c >= C) return;
  float m = acc[c] * invN;
  float v = acc[C + c] * invN - m * m;
  stats[c] = m;
  stats[C + c] = rsqrtf(v + 1e-5f);
}

// --------------------------------------- BN+ReLU+maxpool2 NHWC (x8 vec)
template <int C, int H, int W>
__global__ __launch_bounds__(256) void k_brp(const unsigned short* __restrict__ x,
                                             unsigned short* __restrict__ y,
                                             const float* __restrict__ stats,
                                             const float* __restrict__ g,
                                             const float* __restrict__ be) {
  constexpr int OH = H / 2, OW = W / 2, CV = C / 8;
  int idx = blockIdx.x * 256 + threadIdx.x;   // [b][oy][ox][cv]
  int cv = idx % CV;
  int t = idx / CV;
  int ox = t % OW; t /= OW;
  int oy = t % OH;
  int b = t / OH;
  int c0 = cv * 8;
  const unsigned short* p = x + ((size_t)(b * H + oy * 2) * W + ox * 2) * C + c0;
  f16x8 v00 = *(const f16x8*)p;
  f16x8 v01 = *(const f16x8*)(p + C);
  f16x8 v10 = *(const f16x8*)(p + (size_t)W * C);
  f16x8 v11 = *(const f16x8*)(p + (size_t)W * C + C);
  f16x8 r;
#pragma unroll
  for (int j = 0; j < 8; ++j) {
    int c = c0 + j;
    float m = stats[c], iv = stats[C + c], gg = g[c], bb = be[c];
    float f0 = gg * (((float)v00[j] - m) * iv) + bb;
    float f1 = gg * (((float)v01[j] - m) * iv) + bb;
    float f2 = gg * (((float)v10[j] - m) * iv) + bb;
    float f3 = gg * (((float)v11[j] - m) * iv) + bb;
    f0 = f0 > 0.f ? f0 : 0.f;
    f1 = f1 > 0.f ? f1 : 0.f;
    f2 = f2 > 0.f ? f2 : 0.f;
    f3 = f3 > 0.f ? f3 : 0.f;
    float r01 = f0 > f1 ? f0 : f1;
    float r23 = f2 > f3 ? f2 : f3;
    r[j] = (_Float16)(r01 > r23 ? r01 : r23);
  }
  *(f16x8*)(y + (size_t)idx * 8) = r;
}

// ---- stage-3 BN+ReLU+pool + write into batch-major fc1 activations (fp16)
__global__ __launch_bounds__(256) void k_brp3t(const unsigned short* __restrict__ x,
                                               unsigned short* __restrict__ actT,
                                               const float* __restrict__ stats,
                                               const float* __restrict__ g,
                                               const float* __restrict__ be) {
  __shared__ float tile[64 * 65];
  int s = blockIdx.x;
  int oy = s >> 3, ox = s & 7;
  int ci = threadIdx.x & 63, bq = threadIdx.x >> 6;
  for (int cs = 0; cs < 4; ++cs) {
    int c = cs * 64 + ci;
    float m = stats[c], iv = stats[256 + c], gg = g[c], bb = be[c];
    __syncthreads();
    for (int b = bq; b < 64; b += 4) {
      float mx = 0.f;
#pragma unroll
      for (int qq = 0; qq < 4; ++qq) {
        int yy = oy * 2 + (qq >> 1), xx = ox * 2 + (qq & 1);
        float v = h2f(x[((size_t)(b * 30 + yy) * 16 + xx) * 256 + c]);
        v = gg * ((v - m) * iv) + bb;
        v = v > 0.f ? v : 0.f;
        mx = v > mx ? v : mx;
      }
      tile[ci * 65 + b] = mx;
    }
    __syncthreads();
    for (int e = threadIdx.x; e < 4096; e += 256) {
      int cc = e >> 6, bb2 = e & 63;
      actT[(size_t)bb2 * 30784 + 64 + (cs * 64 + cc) * 120 + s] = f2h(tile[cc * 65 + bb2]);
    }
  }
}

// -------------------- q rows of fc inputs + zero fc1 accumulator + BN accums
__global__ __launch_bounds__(256) void k_qinit(const float* __restrict__ q,
                                               unsigned short* __restrict__ actT,
                                               float* __restrict__ in2T,
                                               float* __restrict__ in3T,
                                               float* __restrict__ z1pre,
                                               float* __restrict__ bnacc) {
  int idx = blockIdx.x * 256 + threadIdx.x;
  if (idx < 32000) z1pre[idx] = 0.f;
  else if (idx < 33024) bnacc[idx - 32000] = 0.f;
  if (idx >= 4096) return;
  int b = idx >> 6, i = idx & 63;
  float v = q[idx];
  actT[(size_t)b * 30784 + i] = f2h(v);
  in2T[i * 64 + b] = v;
  in3T[i * 64 + b] = v;
}

// --------------------------------------------------------- fc1 (MFMA GEMM)
__global__ __launch_bounds__(256) void k_fc1m(const unsigned short* __restrict__ actT,
                                              const float* __restrict__ wgt,
                                              float* __restrict__ z1pre) {
  constexpr int IN = 30784;
  constexpr int KSTEPS = IN / 32;   // 962
  __shared__ float part[4][16][64];
  int tid = threadIdx.x;
  int w = tid >> 6, lane = tid & 63, l15 = lane & 15, q = lane >> 4;
  int ob = blockIdx.x * 16;
  int row = ob + l15; if (row > 499) row = 499;
  int kw = blockIdx.y * 4 + w;      // 0..31
  f32x4 acc[4];
#pragma unroll
  for (int nt = 0; nt < 4; ++nt) acc[nt] = 0.f;
  for (int s = kw; s < KSTEPS; s += 32) {
    int k0 = s * 32;
    const float4* wp = (const float4*)(wgt + (size_t)row * IN + k0 + q * 8);
    float4 wa = wp[0], wb = wp[1];
    f16x8 a;
    a[0] = (_Float16)wa.x; a[1] = (_Float16)wa.y;
    a[2] = (_Float16)wa.z; a[3] = (_Float16)wa.w;
    a[4] = (_Float16)wb.x; a[5] = (_Float16)wb.y;
    a[6] = (_Float16)wb.z; a[7] = (_Float16)wb.w;
#pragma unroll
    for (int nt = 0; nt < 4; ++nt) {
      f16x8 bv = *(const f16x8*)(actT + (size_t)(nt * 16 + l15) * IN + k0 + q * 8);
      acc[nt] = __builtin_amdgcn_mfma_f32_16x16x32_f16(a, bv, acc[nt], 0, 0, 0);
    }
  }
#pragma unroll
  for (int nt = 0; nt < 4; ++nt)
#pragma unroll
    for (int reg = 0; reg < 4; ++reg)
      part[w][q * 4 + reg][nt * 16 + l15] = acc[nt][reg];
  __syncthreads();
  for (int e = tid; e < 1024; e += 256) {
    int m = e >> 6, n = e & 63;
    float sum = part[0][m][n] + part[1][m][n] + part[2][m][n] + part[3][m][n];
    int o = ob + m;
    if (o < 500) atomicAdd(&z1pre[o * 64 + n], sum);
  }
}

__global__ __launch_bounds__(256) void k_fc1ep(const float* __restrict__ z1pre,
                                               const float* __restrict__ bias,
                                               float* __restrict__ in2T) {
  int idx = blockIdx.x * 256 + threadIdx.x;
  if (idx >= 500 * 64) return;
  int o = idx >> 6;
  float v = z1pre[idx] + bias[o];
  in2T[idx + 64 * 64] = v > 0.f ? v : 0.f;
}

__global__ __launch_bounds__(256) void k_fc_small(const float* __restrict__ inT,
                                                  const float* __restrict__ wgt,
                                                  const float* __restrict__ bias,
                                                  float* __restrict__ out,
                                                  int IN, int mode) {
  __shared__ float part[4][64];
  int o = blockIdx.x;
  int lane = threadIdx.x & 63, w = threadIdx.x >> 6;
  float acc = 0.f;
  for (int i = w; i < IN; i += 4)
    acc = fmaf(inT[(size_t)i * 64 + lane], wgt[(size_t)o * IN + i], acc);
  part[w][lane] = acc;
  __syncthreads();
  if (threadIdx.x < 64) {
    float s = part[0][lane] + part[1][lane] + part[2][lane] + part[3][lane] + bias[o];
    if (mode == 0) {
      s = s > 0.f ? s : 0.f;
      out[(64 + o) * 64 + lane] = s;
    } else {
      out[lane * 2 + o] = s;
    }
  }
}

// ============================================================================
extern "C" void kernel_launch(void* const* d_in, const int* in_sizes, int n_in,
                              void* d_out, int out_size, void* d_ws, size_t ws_size,
                              hipStream_t stream) {
  const float* x      = (const float*)d_in[0];
  const float* qvec   = (const float*)d_in[1];
  const float* basis  = (const float*)d_in[2];
  const float* w1a    = (const float*)d_in[3];
  const float* g1a    = (const float*)d_in[5];
  const float* be1a   = (const float*)d_in[6];
  const float* w1b    = (const float*)d_in[7];
  const float* g1b    = (const float*)d_in[9];
  const float* be1b   = (const float*)d_in[10];
  const float* w2a    = (const float*)d_in[11];
  const float* g2a    = (const float*)d_in[13];
  const float* be2a   = (const float*)d_in[14];
  const float* w3a    = (const float*)d_in[15];
  const float* g3a    = (const float*)d_in[17];
  const float* be3a   = (const float*)d_in[18];
  const float* fc1w   = (const float*)d_in[19];
  const float* fc1b   = (const float*)d_in[20];
  const float* fc2w   = (const float*)d_in[21];
  const float* fc2b   = (const float*)d_in[22];
  const float* fc3w   = (const float*)d_in[23];
  const float* fc3b   = (const float*)d_in[24];
  float* out = (float*)d_out;

  char* base = (char*)d_ws;
  constexpr size_t ARENA = 62914560;
  char* arenaA = base;
  char* arenaB = base + ARENA;
  char* sm     = base + 2 * ARENA;

  float*          xd   = (float*)arenaA;
  unsigned short* A    = (unsigned short*)arenaA;  // pre1a NHWC [64][120][64][64] (raw)
  unsigned short* P1   = (unsigned short*)arenaA;  // [64][60][32][64]
  unsigned short* P2   = (unsigned short*)arenaA;  // [64][30][16][128]
  unsigned short* actT = (unsigned short*)arenaA;  // [64][30784] fp16

  float*          feat = (float*)arenaB;           // [64][120][64] fp32
  unsigned short* Bb   = (unsigned short*)arenaB;  // pre1b [64][120][64][64]
  unsigned short* C2   = (unsigned short*)arenaB;  // [64][60][32][128]
  unsigned short* D3   = (unsigned short*)arenaB;  // [64][30][16][256]

  float* in2T = (float*)sm;                    // 144,384 B
  float* in3T = (float*)(sm + 144384);         // 144,384 B
  float* z1p  = (float*)(sm + 288768);         // 128,000 B
  float* ACC  = (float*)(sm + 416768);         // 4,096 B
  float* S1A  = (float*)(sm + 420864);
  float* S1B  = (float*)(sm + 421376);
  float* S2A  = (float*)(sm + 421888);
  float* S3A  = (float*)(sm + 422912);
  unsigned short* WT1 = (unsigned short*)(sm + 424960);   // 204,800 B
  unsigned short* WT2 = (unsigned short*)(sm + 834560);   // 409,600 B
  unsigned short* WT3 = (unsigned short*)(sm + 1653760);  // 1,638,400 B

  k_qinit<<<130, 256, 0, stream>>>(qvec, actT, in2T, in3T, z1p, ACC);
  k_prepw<<<400, 256, 0, stream>>>(w1b, WT1, 64, 64);
  k_prepw<<<800, 256, 0, stream>>>(w2a, WT2, 128, 64);
  k_prepw<<<3200, 256, 0, stream>>>(w3a, WT3, 256, 128);

  k_dct<<<64 * 8, 256, 0, stream>>>(x, basis, xd);
  k_hist<<<4096, 256, 0, stream>>>(xd, feat);

  // conv1a (direct) -> A (raw pre-activations), stats over A
  k_conv1a<<<dim3(32, 64, 8), 256, 0, stream>>>(feat, w1a, A);
  k_bnstatsv<64><<<240, 256, 0, stream>>>(A, ACC, 64);
  k_bnfin<<<1, 64, 0, stream>>>(ACC, S1A, 64, 1.f / 491520.f);

  // conv1b (MFMA, PREBN applies BN1a+ReLU during staging) -> Bb
  k_convM<64, 120, 64, 4, 64, true><<<dim3(30, 64, 1), 256, 0, stream>>>(
      A, WT1, Bb, S1A, g1a, be1a);
  k_bnstatsv<64><<<240, 256, 0, stream>>>(Bb, ACC + 128, 64);
  k_bnfin<<<1, 64, 0, stream>>>(ACC + 128, S1B, 64, 1.f / 491520.f);
  k_brp<64, 120, 64><<<3840, 256, 0, stream>>>(Bb, P1, S1B, g1b, be1b);

  // conv2a -> C2, stats, pool -> P2
  k_convM<64, 60, 32, 4, 128, false><<<dim3(8, 64, 2), 256, 0, stream>>>(
      P1, WT2, C2, S1A, g1a, be1a);
  k_bnstatsv<128><<<240, 256, 0, stream>>>(C2, ACC + 256, 32);
  k_bnfin<<<1, 128, 0, stream>>>(ACC + 256, S2A, 128, 1.f / 122880.f);
  k_brp<128, 60, 32><<<1920, 256, 0, stream>>>(C2, P2, S2A, g2a, be2a);

  // conv3a -> D3, stats, pool+transpose -> actT
  k_convM<128, 30, 16, 4, 256, false><<<dim3(2, 64, 4), 256, 0, stream>>>(
      P2, WT3, D3, S1A, g1a, be1a);
  k_bnstatsv<256><<<240, 256, 0, stream>>>(D3, ACC + 512, 16);
  k_bnfin<<<1, 256, 0, stream>>>(ACC + 512, S3A, 256, 1.f / 30720.f);
  k_qinit<<<130, 256, 0, stream>>>(qvec, actT, in2T, in3T, z1p, ACC);
  k_brp3t<<<120, 256, 0, stream>>>(D3, actT, S3A, g3a, be3a);

  // FC head
  k_fc1m<<<dim3(32, 8), 256, 0, stream>>>(actT, fc1w, z1p);
  k_fc1ep<<<125, 256, 0, stream>>>(z1p, fc1b, in2T);
  k_fc_small<<<500, 256, 0, stream>>>(in2T, fc2w, fc2b, in3T, 564, 0);
  k_fc_small<<<2, 256, 0, stream>>>(in3T, fc3w, fc3b, out, 564, 1);
}